// Round 8
// baseline (432.442 us; speedup 1.0000x reference)
//
#include <hip/hip_runtime.h>
#include <hip/hip_bf16.h>
#include <stdint.h>

#define D_IN 1024
#define D_K  128
#define NBATCH 8
#define SEQ  4096
#define MROWS (NBATCH * SEQ)

typedef __attribute__((ext_vector_type(8))) short bf16x8;
typedef __attribute__((ext_vector_type(4))) float f32x4;

__device__ __forceinline__ unsigned short f32_to_bf16(float x) {
    union { float f; uint32_t u; } v; v.f = x;
    uint32_t r = 0x7FFFu + ((v.u >> 16) & 1u);
    return (unsigned short)((v.u + r) >> 16);
}

__device__ __forceinline__ bf16x8 cvt8(float4 lo, float4 hi) {
    bf16x8 r;
    r[0] = (short)f32_to_bf16(lo.x); r[1] = (short)f32_to_bf16(lo.y);
    r[2] = (short)f32_to_bf16(lo.z); r[3] = (short)f32_to_bf16(lo.w);
    r[4] = (short)f32_to_bf16(hi.x); r[5] = (short)f32_to_bf16(hi.y);
    r[6] = (short)f32_to_bf16(hi.z); r[7] = (short)f32_to_bf16(hi.w);
    return r;
}

// ---------------- W pre-convert (unchanged, passing) ----------------
// Wt[p][kc=0..127][n=0..127] = 8 bf16 of W_p[n][kc*8 .. kc*8+8)  (Wq scaled)
__global__ __launch_bounds__(256)
void wconv_kernel(const float* __restrict__ Wq, const float* __restrict__ Wk,
                  const float* __restrict__ Wv, unsigned short* __restrict__ Wt)
{
    const int t  = blockIdx.x * 256 + threadIdx.x;
    const int n  = t & 127;
    const int kc = (t >> 7) & 127;
    const int p  = t >> 14;
    const float* __restrict__ W = (p == 0) ? Wq : (p == 1) ? Wk : Wv;
    const float sc = (p == 0) ? (1.44269504088896f * 0.0883883476483184f) : 1.0f;
    const float4* src = reinterpret_cast<const float4*>(W + (size_t)n * D_IN + kc * 8);
    float4 a = src[0], b = src[1];
    uint4 o;
    o.x = (uint32_t)f32_to_bf16(a.x * sc) | ((uint32_t)f32_to_bf16(a.y * sc) << 16);
    o.y = (uint32_t)f32_to_bf16(a.z * sc) | ((uint32_t)f32_to_bf16(a.w * sc) << 16);
    o.z = (uint32_t)f32_to_bf16(b.x * sc) | ((uint32_t)f32_to_bf16(b.y * sc) << 16);
    o.w = (uint32_t)f32_to_bf16(b.z * sc) | ((uint32_t)f32_to_bf16(b.w * sc) << 16);
    *reinterpret_cast<uint4*>(Wt + (size_t)t * 8) = o;
}

// ---------------- projection GEMM: Y = X * W^T (R7 structure, unchanged) ----
#define RBM 32

__global__ __launch_bounds__(256, 2)
void proj_kernel(const float* __restrict__ Xq, const float* __restrict__ Xk,
                 const float* __restrict__ Xv,
                 const unsigned short* __restrict__ Wt,
                 unsigned short* __restrict__ qh, unsigned short* __restrict__ kh,
                 unsigned short* __restrict__ vhT)
{
    const int p = blockIdx.y;
    const float* __restrict__ X = (p == 0) ? Xq : (p == 1) ? Xk : Xv;
    const unsigned short* __restrict__ Wtp = Wt + (size_t)p * 128 * 128 * 8;

    __shared__ unsigned short As[RBM * 1024];   // 64KB  [row][k] bf16, XOR-swizzled
    __shared__ unsigned short Bs[8 * 128 * 8];  // 16KB  [kc_local][n][8], n^kc swizzle

    const int tid  = threadIdx.x;
    const int lane = tid & 63;
    const int wave = tid >> 6;
    const int lrow = lane & 15;
    const int g    = lane >> 4;
    const int wr   = (wave >> 1) * 16;
    const int wc   = (wave & 1) * 64;
    const int wbase = blockIdx.x * RBM;

    // ---- Phase 1: stage 8 full rows per wave (row-linear DRAM reads) ----
    {
        const int r0 = wave * 8;
        const char* rowp = reinterpret_cast<const char*>(
            X + (size_t)(wbase + r0) * D_IN) + lane * 32;
        float4 a0 = *reinterpret_cast<const float4*>(rowp);
        float4 a1 = *reinterpret_cast<const float4*>(rowp + 16);
        float4 a2 = *reinterpret_cast<const float4*>(rowp + 2048);
        float4 a3 = *reinterpret_cast<const float4*>(rowp + 2048 + 16);
        #pragma unroll
        for (int i = 0; i < 8; ++i) {
            float4 c0 = a0, c1 = a1, c2 = a2, c3 = a3;
            if (i < 7) {
                const char* np = rowp + (size_t)(i + 1) * 4096;
                a0 = *reinterpret_cast<const float4*>(np);
                a1 = *reinterpret_cast<const float4*>(np + 16);
                a2 = *reinterpret_cast<const float4*>(np + 2048);
                a3 = *reinterpret_cast<const float4*>(np + 2048 + 16);
            }
            const int r = r0 + i;
            char* base = reinterpret_cast<char*>(As) + r * 2048;
            const int swz = (r & 7) << 4;
            *reinterpret_cast<bf16x8*>(base + ((lane * 16) ^ swz)) = cvt8(c0, c1);
            *reinterpret_cast<bf16x8*>(base + ((1024 + lane * 16) ^ swz)) = cvt8(c2, c3);
        }
    }

    // ---- stage B pass 0 (16KB linear from Wt slice) ----
    {
        const uint4* src = reinterpret_cast<const uint4*>(Wtp) + tid * 4;
        #pragma unroll
        for (int j = 0; j < 4; ++j) {
            uint4 v = src[j];
            const int i  = tid * 4 + j;           // entry index (16B each)
            const int kc = i >> 7, n = i & 127;
            *reinterpret_cast<uint4*>(reinterpret_cast<char*>(Bs) +
                kc * 2048 + ((n ^ kc) * 16)) = v;
        }
    }
    __syncthreads();

    // ---- Phase 2: 16 passes x 2 k-steps, all operands from LDS ----
    f32x4 acc[4];
    #pragma unroll
    for (int ni = 0; ni < 4; ++ni) acc[ni] = (f32x4){0.f, 0.f, 0.f, 0.f};

    const int arow = wr + lrow;
    const char* abase = reinterpret_cast<const char*>(As) + arow * 2048;
    const int aswz = (arow & 7) << 4;

    for (int q = 0; q < 16; ++q) {
        // issue next B slice loads early (T14 async split)
        uint4 nb0, nb1, nb2, nb3;
        if (q < 15) {
            const uint4* src = reinterpret_cast<const uint4*>(
                Wtp + (size_t)(q + 1) * 8192) + tid * 4;
            nb0 = src[0]; nb1 = src[1]; nb2 = src[2]; nb3 = src[3];
        }

        // 2 k-steps from LDS
        #pragma unroll
        for (int s = 0; s < 2; ++s) {
            const int t = 2 * q + s;              // global k-step
            const int kcl = s * 4 + g;            // local kc in Bs
            bf16x8 af = *reinterpret_cast<const bf16x8*>(
                abase + ((t * 64 + g * 16) ^ aswz));
            #pragma unroll
            for (int ni = 0; ni < 4; ++ni) {
                const int n = wc + ni * 16 + lrow;
                bf16x8 bf = *reinterpret_cast<const bf16x8*>(
                    reinterpret_cast<const char*>(Bs) + kcl * 2048 + ((n ^ kcl) * 16));
                acc[ni] = __builtin_amdgcn_mfma_f32_16x16x32_bf16(af, bf, acc[ni], 0, 0, 0);
            }
        }

        __syncthreads();   // all waves done reading Bs(q)
        if (q < 15) {
            #pragma unroll
            for (int j = 0; j < 4; ++j) {
                uint4 v = (j == 0) ? nb0 : (j == 1) ? nb1 : (j == 2) ? nb2 : nb3;
                const int i  = tid * 4 + j;
                const int kc = i >> 7, n = i & 127;
                *reinterpret_cast<uint4*>(reinterpret_cast<char*>(Bs) +
                    kc * 2048 + ((n ^ kc) * 16)) = v;
            }
            __syncthreads();
        }
    }

    // ---- epilogue: col = wc+ni*16+lrow, row = wbase+wr+g*4+r ----
    if (p < 2) {
        unsigned short* __restrict__ Y = (p == 0) ? qh : kh;
        const int rbase = wbase + wr + g * 4;
        #pragma unroll
        for (int ni = 0; ni < 4; ++ni) {
            const int n = wc + ni * 16 + lrow;
            #pragma unroll
            for (int r = 0; r < 4; ++r)
                Y[(size_t)(rbase + r) * D_K + n] = f32_to_bf16(acc[ni][r]);
        }
    } else {
        const int b  = wbase >> 12;
        const int s  = (wbase & 4095) + wr + g * 4;
        #pragma unroll
        for (int ni = 0; ni < 4; ++ni) {
            const int d = wc + ni * 16 + lrow;
            uint2 t;
            t.x = (uint32_t)f32_to_bf16(acc[ni][0]) |
                  ((uint32_t)f32_to_bf16(acc[ni][1]) << 16);
            t.y = (uint32_t)f32_to_bf16(acc[ni][2]) |
                  ((uint32_t)f32_to_bf16(acc[ni][3]) << 16);
            *reinterpret_cast<uint2*>(vhT + ((size_t)(b * D_K + d) << 12) + s) = t;
        }
    }
}

// ---------------- flash attention v6b: QBLK=64, dbuf K/V (staging FIXED) ----
#define KVB 64

__global__ __launch_bounds__(256, 2)
void attn_kernel(const unsigned short* __restrict__ qh,
                 const unsigned short* __restrict__ kh,
                 const unsigned short* __restrict__ vhT,
                 float* __restrict__ out)
{
    __shared__ unsigned short Ks[2][KVB * D_K];   // 2 x 16KB, swizzled
    __shared__ unsigned short Vs[2][D_K * KVB];   // 2 x 16KB, swizzled (V^T)
    __shared__ unsigned short Ps[4][16 * KVB];    // per-wave [16][64], 2KB each

    const int tid  = threadIdx.x;
    const int lane = tid & 63;
    const int wave = tid >> 6;
    const int b    = blockIdx.x & 7;     // batch -> XCD L2 locality
    const int qt   = blockIdx.x >> 3;
    const int q0   = qt * 64 + wave * 16;
    const int lrow = lane & 15;
    const int g4   = (lane >> 4) << 2;
    const int lk16 = (lane >> 4) * 16;

    // hoisted Q fragments (16 rows per wave)
    bf16x8 qf[4];
    {
        const char* base = reinterpret_cast<const char*>(
            qh + (size_t)(b * SEQ + q0 + lrow) * D_K);
        #pragma unroll
        for (int ks = 0; ks < 4; ++ks)
            qf[ks] = *reinterpret_cast<const bf16x8*>(base + ks * 64 + lk16);
    }

    f32x4 o[8];
    #pragma unroll
    for (int df = 0; df < 8; ++df) o[df] = (f32x4){0.f, 0.f, 0.f, 0.f};
    float lsum[4] = {0.f, 0.f, 0.f, 0.f};

    const unsigned short* __restrict__ Kb = kh + (size_t)b * SEQ * D_K;
    const unsigned short* __restrict__ Vb = vhT + (size_t)b * D_K * SEQ;
    unsigned short* const Pw = Ps[wave];

    // staging: K row = 256B (4 thr x 64B), V^T row = 128B (2 thr x 64B)
    const int krow = tid >> 2, kcb = (tid & 3) * 64;     // 4 x 16B per thread (K)
    const int vrow = tid >> 1, vcb = (tid & 1) * 64;     // 4 x 16B per thread (V)
    const int kswz = (krow & 7) << 4, vswz = (vrow & 7) << 4;

    // prologue: stage tile 0 into buffer 0 (full coverage)
    {
        const char* ksrc = reinterpret_cast<const char*>(Kb + (size_t)krow * D_K) + kcb;
        const char* vsrc = reinterpret_cast<const char*>(Vb + (size_t)vrow * SEQ) + vcb;
        #pragma unroll
        for (int j = 0; j < 4; ++j) {
            uint4 kv = *reinterpret_cast<const uint4*>(ksrc + j * 16);
            uint4 vv = *reinterpret_cast<const uint4*>(vsrc + j * 16);
            *reinterpret_cast<uint4*>(reinterpret_cast<char*>(Ks[0]) +
                krow * 256 + ((kcb + j * 16) ^ kswz)) = kv;
            *reinterpret_cast<uint4*>(reinterpret_cast<char*>(Vs[0]) +
                vrow * 128 + ((vcb + j * 16) ^ vswz)) = vv;
        }
    }
    __syncthreads();

    int cur = 0;
    for (int it = 0; it < SEQ / KVB; ++it) {
        const int s0n = (it + 1) * KVB;
        // issue next-tile loads early (T14 async split)
        uint4 kr[4], vr4[4];
        if (s0n < SEQ) {
            const char* ksrc = reinterpret_cast<const char*>(
                Kb + (size_t)(s0n + krow) * D_K) + kcb;
            const char* vsrc = reinterpret_cast<const char*>(
                Vb + (size_t)vrow * SEQ + s0n) + vcb;
            #pragma unroll
            for (int j = 0; j < 4; ++j) {
                kr[j]  = *reinterpret_cast<const uint4*>(ksrc + j * 16);
                vr4[j] = *reinterpret_cast<const uint4*>(vsrc + j * 16);
            }
        }

        // QK^T: sc[sf] = Q(16x128) . K(64x128)^T
        f32x4 sc[4];
        #pragma unroll
        for (int sf = 0; sf < 4; ++sf) sc[sf] = (f32x4){0.f, 0.f, 0.f, 0.f};
        #pragma unroll
        for (int ks = 0; ks < 4; ++ks) {
            #pragma unroll
            for (int sf = 0; sf < 4; ++sf) {
                const int row = sf * 16 + lrow;
                bf16x8 kf = *reinterpret_cast<const bf16x8*>(
                    reinterpret_cast<const char*>(Ks[cur]) + row * 256 +
                    ((ks * 64 + lk16) ^ ((row & 7) << 4)));
                sc[sf] = __builtin_amdgcn_mfma_f32_16x16x32_bf16(qf[ks], kf, sc[sf], 0, 0, 0);
            }
        }

        // softmax numerators; spill P to per-wave LDS (same-wave, no barrier)
        #pragma unroll
        for (int sf = 0; sf < 4; ++sf) {
            #pragma unroll
            for (int r = 0; r < 4; ++r) {
                float pv = exp2f(sc[sf][r]);
                lsum[r] += pv;
                const int prow = g4 + r;
                const int pcol = (sf * 16 + lrow) * 2;
                *reinterpret_cast<unsigned short*>(
                    reinterpret_cast<char*>(Pw) + prow * 128 +
                    (pcol ^ ((prow & 7) << 4))) = f32_to_bf16(pv);
            }
        }

        // PV: o[df] += P(16x64) . V(64x128)
        #pragma unroll
        for (int ks = 0; ks < 2; ++ks) {
            bf16x8 pf = *reinterpret_cast<const bf16x8*>(
                reinterpret_cast<const char*>(Pw) + lrow * 128 +
                ((ks * 64 + lk16) ^ ((lrow & 7) << 4)));
            #pragma unroll
            for (int df = 0; df < 8; ++df) {
                const int vr = df * 16 + lrow;
                bf16x8 vf = *reinterpret_cast<const bf16x8*>(
                    reinterpret_cast<const char*>(Vs[cur]) + vr * 128 +
                    ((ks * 64 + lk16) ^ ((vr & 7) << 4)));
                o[df] = __builtin_amdgcn_mfma_f32_16x16x32_bf16(pf, vf, o[df], 0, 0, 0);
            }
        }

        __syncthreads();   // everyone done with buffers of tile `it`
        if (s0n < SEQ) {
            const int nb = cur ^ 1;
            #pragma unroll
            for (int j = 0; j < 4; ++j) {
                *reinterpret_cast<uint4*>(reinterpret_cast<char*>(Ks[nb]) +
                    krow * 256 + ((kcb + j * 16) ^ kswz)) = kr[j];
                *reinterpret_cast<uint4*>(reinterpret_cast<char*>(Vs[nb]) +
                    vrow * 128 + ((vcb + j * 16) ^ vswz)) = vr4[j];
            }
            __syncthreads();
            cur = nb;
        }
    }

    // finalize: reduce row-sums across the 16-lane group, divide, store fp32
    #pragma unroll
    for (int r = 0; r < 4; ++r) {
        float s = lsum[r];
        s += __shfl_xor(s, 1);
        s += __shfl_xor(s, 2);
        s += __shfl_xor(s, 4);
        s += __shfl_xor(s, 8);
        float inv = 1.0f / s;
        const int row = q0 + g4 + r;
        float* ob = out + (size_t)(b * SEQ + row) * D_K + lrow;
        #pragma unroll
        for (int df = 0; df < 8; ++df)
            ob[df * 16] = o[df][r] * inv;
    }
}

extern "C" void kernel_launch(void* const* d_in, const int* in_sizes, int n_in,
                              void* d_out, int out_size, void* d_ws, size_t ws_size,
                              hipStream_t stream)
{
    (void)in_sizes; (void)n_in; (void)out_size; (void)ws_size;
    const float* q  = (const float*)d_in[0];
    const float* k  = (const float*)d_in[1];
    const float* v  = (const float*)d_in[2];
    const float* Wq = (const float*)d_in[3];
    const float* Wk = (const float*)d_in[4];
    const float* Wv = (const float*)d_in[5];

    unsigned short* qh  = (unsigned short*)d_ws;                 // [32768][128] bf16
    unsigned short* kh  = qh + (size_t)MROWS * D_K;              // [32768][128] bf16
    unsigned short* vhT = kh + (size_t)MROWS * D_K;              // [8][128][4096] bf16
    unsigned short* Wt  = vhT + (size_t)MROWS * D_K;             // [3][128][128][8] bf16

    wconv_kernel<<<dim3(192), 256, 0, stream>>>(Wq, Wk, Wv, Wt);
    proj_kernel<<<dim3(MROWS / RBM, 3), 256, 0, stream>>>(q, k, v, Wt, qh, kh, vhT);
    attn_kernel<<<dim3(NBATCH * (SEQ / 64)), 256, 0, stream>>>(qh, kh, vhT, (float*)d_out);
}

// Round 9
// 359.683 us; speedup vs baseline: 1.2023x; 1.2023x over previous
//
#include <hip/hip_runtime.h>
#include <hip/hip_bf16.h>
#include <stdint.h>

#define D_IN 1024
#define D_K  128
#define NBATCH 8
#define SEQ  4096
#define MROWS (NBATCH * SEQ)

typedef __attribute__((ext_vector_type(8))) short bf16x8;
typedef __attribute__((ext_vector_type(4))) float f32x4;

__device__ __forceinline__ unsigned short f32_to_bf16(float x) {
    union { float f; uint32_t u; } v; v.f = x;
    uint32_t r = 0x7FFFu + ((v.u >> 16) & 1u);
    return (unsigned short)((v.u + r) >> 16);
}

__device__ __forceinline__ bf16x8 cvt8(float4 lo, float4 hi) {
    bf16x8 r;
    r[0] = (short)f32_to_bf16(lo.x); r[1] = (short)f32_to_bf16(lo.y);
    r[2] = (short)f32_to_bf16(lo.z); r[3] = (short)f32_to_bf16(lo.w);
    r[4] = (short)f32_to_bf16(hi.x); r[5] = (short)f32_to_bf16(hi.y);
    r[6] = (short)f32_to_bf16(hi.z); r[7] = (short)f32_to_bf16(hi.w);
    return r;
}

// ---------------- W pre-convert (unchanged, passing) ----------------
// Wt[p][kc=0..127][n=0..127] = 8 bf16 of W_p[n][kc*8 .. kc*8+8)  (Wq scaled)
__global__ __launch_bounds__(256)
void wconv_kernel(const float* __restrict__ Wq, const float* __restrict__ Wk,
                  const float* __restrict__ Wv, unsigned short* __restrict__ Wt)
{
    const int t  = blockIdx.x * 256 + threadIdx.x;
    const int n  = t & 127;
    const int kc = (t >> 7) & 127;
    const int p  = t >> 14;
    const float* __restrict__ W = (p == 0) ? Wq : (p == 1) ? Wk : Wv;
    const float sc = (p == 0) ? (1.44269504088896f * 0.0883883476483184f) : 1.0f;
    const float4* src = reinterpret_cast<const float4*>(W + (size_t)n * D_IN + kc * 8);
    float4 a = src[0], b = src[1];
    uint4 o;
    o.x = (uint32_t)f32_to_bf16(a.x * sc) | ((uint32_t)f32_to_bf16(a.y * sc) << 16);
    o.y = (uint32_t)f32_to_bf16(a.z * sc) | ((uint32_t)f32_to_bf16(a.w * sc) << 16);
    o.z = (uint32_t)f32_to_bf16(b.x * sc) | ((uint32_t)f32_to_bf16(b.y * sc) << 16);
    o.w = (uint32_t)f32_to_bf16(b.z * sc) | ((uint32_t)f32_to_bf16(b.w * sc) << 16);
    *reinterpret_cast<uint4*>(Wt + (size_t)t * 8) = o;
}

// ---------------- projection GEMM (R8, passing, ~100us — FROZEN) ----------
#define RBM 32

__global__ __launch_bounds__(256, 2)
void proj_kernel(const float* __restrict__ Xq, const float* __restrict__ Xk,
                 const float* __restrict__ Xv,
                 const unsigned short* __restrict__ Wt,
                 unsigned short* __restrict__ qh, unsigned short* __restrict__ kh,
                 unsigned short* __restrict__ vhT)
{
    const int p = blockIdx.y;
    const float* __restrict__ X = (p == 0) ? Xq : (p == 1) ? Xk : Xv;
    const unsigned short* __restrict__ Wtp = Wt + (size_t)p * 128 * 128 * 8;

    __shared__ unsigned short As[RBM * 1024];   // 64KB  [row][k] bf16, XOR-swizzled
    __shared__ unsigned short Bs[8 * 128 * 8];  // 16KB  [kc_local][n][8], n^kc swizzle

    const int tid  = threadIdx.x;
    const int lane = tid & 63;
    const int wave = tid >> 6;
    const int lrow = lane & 15;
    const int g    = lane >> 4;
    const int wr   = (wave >> 1) * 16;
    const int wc   = (wave & 1) * 64;
    const int wbase = blockIdx.x * RBM;

    // ---- Phase 1: stage 8 full rows per wave (row-linear DRAM reads) ----
    {
        const int r0 = wave * 8;
        const char* rowp = reinterpret_cast<const char*>(
            X + (size_t)(wbase + r0) * D_IN) + lane * 32;
        float4 a0 = *reinterpret_cast<const float4*>(rowp);
        float4 a1 = *reinterpret_cast<const float4*>(rowp + 16);
        float4 a2 = *reinterpret_cast<const float4*>(rowp + 2048);
        float4 a3 = *reinterpret_cast<const float4*>(rowp + 2048 + 16);
        #pragma unroll
        for (int i = 0; i < 8; ++i) {
            float4 c0 = a0, c1 = a1, c2 = a2, c3 = a3;
            if (i < 7) {
                const char* np = rowp + (size_t)(i + 1) * 4096;
                a0 = *reinterpret_cast<const float4*>(np);
                a1 = *reinterpret_cast<const float4*>(np + 16);
                a2 = *reinterpret_cast<const float4*>(np + 2048);
                a3 = *reinterpret_cast<const float4*>(np + 2048 + 16);
            }
            const int r = r0 + i;
            char* base = reinterpret_cast<char*>(As) + r * 2048;
            const int swz = (r & 7) << 4;
            *reinterpret_cast<bf16x8*>(base + ((lane * 16) ^ swz)) = cvt8(c0, c1);
            *reinterpret_cast<bf16x8*>(base + ((1024 + lane * 16) ^ swz)) = cvt8(c2, c3);
        }
    }

    // ---- stage B pass 0 (16KB linear from Wt slice) ----
    {
        const uint4* src = reinterpret_cast<const uint4*>(Wtp) + tid * 4;
        #pragma unroll
        for (int j = 0; j < 4; ++j) {
            uint4 v = src[j];
            const int i  = tid * 4 + j;           // entry index (16B each)
            const int kc = i >> 7, n = i & 127;
            *reinterpret_cast<uint4*>(reinterpret_cast<char*>(Bs) +
                kc * 2048 + ((n ^ kc) * 16)) = v;
        }
    }
    __syncthreads();

    // ---- Phase 2: 16 passes x 2 k-steps, all operands from LDS ----
    f32x4 acc[4];
    #pragma unroll
    for (int ni = 0; ni < 4; ++ni) acc[ni] = (f32x4){0.f, 0.f, 0.f, 0.f};

    const int arow = wr + lrow;
    const char* abase = reinterpret_cast<const char*>(As) + arow * 2048;
    const int aswz = (arow & 7) << 4;

    for (int q = 0; q < 16; ++q) {
        // issue next B slice loads early (async split)
        uint4 nb0, nb1, nb2, nb3;
        if (q < 15) {
            const uint4* src = reinterpret_cast<const uint4*>(
                Wtp + (size_t)(q + 1) * 8192) + tid * 4;
            nb0 = src[0]; nb1 = src[1]; nb2 = src[2]; nb3 = src[3];
        }

        // 2 k-steps from LDS
        #pragma unroll
        for (int s = 0; s < 2; ++s) {
            const int t = 2 * q + s;              // global k-step
            const int kcl = s * 4 + g;            // local kc in Bs
            bf16x8 af = *reinterpret_cast<const bf16x8*>(
                abase + ((t * 64 + g * 16) ^ aswz));
            #pragma unroll
            for (int ni = 0; ni < 4; ++ni) {
                const int n = wc + ni * 16 + lrow;
                bf16x8 bf = *reinterpret_cast<const bf16x8*>(
                    reinterpret_cast<const char*>(Bs) + kcl * 2048 + ((n ^ kcl) * 16));
                acc[ni] = __builtin_amdgcn_mfma_f32_16x16x32_bf16(af, bf, acc[ni], 0, 0, 0);
            }
        }

        __syncthreads();   // all waves done reading Bs(q)
        if (q < 15) {
            #pragma unroll
            for (int j = 0; j < 4; ++j) {
                uint4 v = (j == 0) ? nb0 : (j == 1) ? nb1 : (j == 2) ? nb2 : nb3;
                const int i  = tid * 4 + j;
                const int kc = i >> 7, n = i & 127;
                *reinterpret_cast<uint4*>(reinterpret_cast<char*>(Bs) +
                    kc * 2048 + ((n ^ kc) * 16)) = v;
            }
            __syncthreads();
        }
    }

    // ---- epilogue: col = wc+ni*16+lrow, row = wbase+wr+g*4+r ----
    if (p < 2) {
        unsigned short* __restrict__ Y = (p == 0) ? qh : kh;
        const int rbase = wbase + wr + g * 4;
        #pragma unroll
        for (int ni = 0; ni < 4; ++ni) {
            const int n = wc + ni * 16 + lrow;
            #pragma unroll
            for (int r = 0; r < 4; ++r)
                Y[(size_t)(rbase + r) * D_K + n] = f32_to_bf16(acc[ni][r]);
        }
    } else {
        const int b  = wbase >> 12;
        const int s  = (wbase & 4095) + wr + g * 4;
        #pragma unroll
        for (int ni = 0; ni < 4; ++ni) {
            const int d = wc + ni * 16 + lrow;
            uint2 t;
            t.x = (uint32_t)f32_to_bf16(acc[ni][0]) |
                  ((uint32_t)f32_to_bf16(acc[ni][1]) << 16);
            t.y = (uint32_t)f32_to_bf16(acc[ni][2]) |
                  ((uint32_t)f32_to_bf16(acc[ni][3]) << 16);
            *reinterpret_cast<uint2*>(vhT + ((size_t)(b * D_K + d) << 12) + s) = t;
        }
    }
}

// ---------------- flash attention v9: QBLK=64, single-buffer, direct staging --
// (R8's reg-staged prefetch caused ~230MB scratch writes; reverted to R5's
// proven global->LDS staging between barriers, kept QBLK=64 / 512 blocks.)
#define KVB 64

__global__ __launch_bounds__(256, 2)
void attn_kernel(const unsigned short* __restrict__ qh,
                 const unsigned short* __restrict__ kh,
                 const unsigned short* __restrict__ vhT,
                 float* __restrict__ out)
{
    __shared__ unsigned short Ks[KVB * D_K];    // 16KB, swizzled
    __shared__ unsigned short Vs[D_K * KVB];    // 16KB, swizzled (V^T)
    __shared__ unsigned short Ps[4][16 * KVB];  // per-wave [16][64], 2KB each

    const int tid  = threadIdx.x;
    const int lane = tid & 63;
    const int wave = tid >> 6;
    const int b    = blockIdx.x & 7;     // batch -> XCD L2 locality
    const int qt   = blockIdx.x >> 3;
    const int q0   = qt * 64 + wave * 16;
    const int lrow = lane & 15;
    const int g4   = (lane >> 4) << 2;
    const int lk16 = (lane >> 4) * 16;

    // hoisted Q fragments (16 rows per wave)
    bf16x8 qf[4];
    {
        const char* base = reinterpret_cast<const char*>(
            qh + (size_t)(b * SEQ + q0 + lrow) * D_K);
        #pragma unroll
        for (int ks = 0; ks < 4; ++ks)
            qf[ks] = *reinterpret_cast<const bf16x8*>(base + ks * 64 + lk16);
    }

    f32x4 o[8];
    #pragma unroll
    for (int df = 0; df < 8; ++df) o[df] = (f32x4){0.f, 0.f, 0.f, 0.f};
    float lsum[4] = {0.f, 0.f, 0.f, 0.f};

    const unsigned short* __restrict__ Kb = kh + (size_t)b * SEQ * D_K;
    const unsigned short* __restrict__ Vb = vhT + (size_t)b * D_K * SEQ;
    unsigned short* const Pw = Ps[wave];

    for (int s0 = 0; s0 < SEQ; s0 += KVB) {
        __syncthreads();
        // stage K tile [64][128] (R5-proven loop, full 16KB coverage)
        #pragma unroll
        for (int i = 0; i < 4; ++i) {
            int slot = i * 256 + tid;
            int row  = slot >> 4;
            int cb   = (slot & 15) * 16;
            uint4 t = *reinterpret_cast<const uint4*>(
                reinterpret_cast<const char*>(Kb + (size_t)(s0 + row) * D_K) + cb);
            *reinterpret_cast<uint4*>(reinterpret_cast<char*>(Ks) +
                row * 256 + (cb ^ ((row & 7) << 4))) = t;
        }
        // stage V^T tile [128][64] (R5-proven loop)
        #pragma unroll
        for (int i = 0; i < 4; ++i) {
            int slot = i * 256 + tid;
            int row  = slot >> 3;
            int cb   = (slot & 7) * 16;
            uint4 t = *reinterpret_cast<const uint4*>(
                reinterpret_cast<const char*>(Vb + (size_t)row * SEQ + s0) + cb);
            *reinterpret_cast<uint4*>(reinterpret_cast<char*>(Vs) +
                row * 128 + (cb ^ ((row & 7) << 4))) = t;
        }
        __syncthreads();

        // QK^T: sc[sf] = Q(16x128) . K(64x128)^T
        f32x4 sc[4];
        #pragma unroll
        for (int sf = 0; sf < 4; ++sf) sc[sf] = (f32x4){0.f, 0.f, 0.f, 0.f};
        #pragma unroll
        for (int ks = 0; ks < 4; ++ks) {
            #pragma unroll
            for (int sf = 0; sf < 4; ++sf) {
                const int row = sf * 16 + lrow;
                bf16x8 kf = *reinterpret_cast<const bf16x8*>(
                    reinterpret_cast<const char*>(Ks) + row * 256 +
                    ((ks * 64 + lk16) ^ ((row & 7) << 4)));
                sc[sf] = __builtin_amdgcn_mfma_f32_16x16x32_bf16(qf[ks], kf, sc[sf], 0, 0, 0);
            }
        }

        // softmax numerators; spill P to per-wave LDS (same-wave, no barrier)
        #pragma unroll
        for (int sf = 0; sf < 4; ++sf) {
            #pragma unroll
            for (int r = 0; r < 4; ++r) {
                float pv = exp2f(sc[sf][r]);
                lsum[r] += pv;
                const int prow = g4 + r;
                const int pcol = (sf * 16 + lrow) * 2;
                *reinterpret_cast<unsigned short*>(
                    reinterpret_cast<char*>(Pw) + prow * 128 +
                    (pcol ^ ((prow & 7) << 4))) = f32_to_bf16(pv);
            }
        }

        // PV: o[df] += P(16x64) . V(64x128)
        #pragma unroll
        for (int ks = 0; ks < 2; ++ks) {
            bf16x8 pf = *reinterpret_cast<const bf16x8*>(
                reinterpret_cast<const char*>(Pw) + lrow * 128 +
                ((ks * 64 + lk16) ^ ((lrow & 7) << 4)));
            #pragma unroll
            for (int df = 0; df < 8; ++df) {
                const int vr = df * 16 + lrow;
                bf16x8 vf = *reinterpret_cast<const bf16x8*>(
                    reinterpret_cast<const char*>(Vs) + vr * 128 +
                    ((ks * 64 + lk16) ^ ((vr & 7) << 4)));
                o[df] = __builtin_amdgcn_mfma_f32_16x16x32_bf16(pf, vf, o[df], 0, 0, 0);
            }
        }
    }

    // finalize: reduce row-sums across the 16-lane group, divide, store fp32
    #pragma unroll
    for (int r = 0; r < 4; ++r) {
        float s = lsum[r];
        s += __shfl_xor(s, 1);
        s += __shfl_xor(s, 2);
        s += __shfl_xor(s, 4);
        s += __shfl_xor(s, 8);
        float inv = 1.0f / s;
        const int row = q0 + g4 + r;
        float* ob = out + (size_t)(b * SEQ + row) * D_K + lrow;
        #pragma unroll
        for (int df = 0; df < 8; ++df)
            ob[df * 16] = o[df][r] * inv;
    }
}

extern "C" void kernel_launch(void* const* d_in, const int* in_sizes, int n_in,
                              void* d_out, int out_size, void* d_ws, size_t ws_size,
                              hipStream_t stream)
{
    (void)in_sizes; (void)n_in; (void)out_size; (void)ws_size;
    const float* q  = (const float*)d_in[0];
    const float* k  = (const float*)d_in[1];
    const float* v  = (const float*)d_in[2];
    const float* Wq = (const float*)d_in[3];
    const float* Wk = (const float*)d_in[4];
    const float* Wv = (const float*)d_in[5];

    unsigned short* qh  = (unsigned short*)d_ws;                 // [32768][128] bf16
    unsigned short* kh  = qh + (size_t)MROWS * D_K;              // [32768][128] bf16
    unsigned short* vhT = kh + (size_t)MROWS * D_K;              // [8][128][4096] bf16
    unsigned short* Wt  = vhT + (size_t)MROWS * D_K;             // [3][128][128][8] bf16

    wconv_kernel<<<dim3(192), 256, 0, stream>>>(Wq, Wk, Wv, Wt);
    proj_kernel<<<dim3(MROWS / RBM, 3), 256, 0, stream>>>(q, k, v, Wt, qh, kh, vhT);
    attn_kernel<<<dim3(NBATCH * (SEQ / 64)), 256, 0, stream>>>(qh, kh, vhT, (float*)d_out);
}

// Round 10
// 240.693 us; speedup vs baseline: 1.7967x; 1.4944x over previous
//
#include <hip/hip_runtime.h>
#include <hip/hip_bf16.h>
#include <stdint.h>

#define D_IN 1024
#define D_K  128
#define NBATCH 8
#define SEQ  4096
#define MROWS (NBATCH * SEQ)

typedef __attribute__((ext_vector_type(8))) short bf16x8;
typedef __attribute__((ext_vector_type(4))) float f32x4;

__device__ __forceinline__ unsigned short f32_to_bf16(float x) {
    union { float f; uint32_t u; } v; v.f = x;
    uint32_t r = 0x7FFFu + ((v.u >> 16) & 1u);
    return (unsigned short)((v.u + r) >> 16);
}

__device__ __forceinline__ bf16x8 cvt8(float4 lo, float4 hi) {
    bf16x8 r;
    r[0] = (short)f32_to_bf16(lo.x); r[1] = (short)f32_to_bf16(lo.y);
    r[2] = (short)f32_to_bf16(lo.z); r[3] = (short)f32_to_bf16(lo.w);
    r[4] = (short)f32_to_bf16(hi.x); r[5] = (short)f32_to_bf16(hi.y);
    r[6] = (short)f32_to_bf16(hi.z); r[7] = (short)f32_to_bf16(hi.w);
    return r;
}

__device__ __forceinline__ void gload16(const void* src, void* lds) {
    __builtin_amdgcn_global_load_lds(
        (const __attribute__((address_space(1))) void*)src,
        (__attribute__((address_space(3))) void*)lds, 16, 0, 0);
}

// ---------------- W pre-convert (unchanged, passing) ----------------
// Wt[p][kc=0..127][n=0..127] = 8 bf16 of W_p[n][kc*8 .. kc*8+8)  (Wq scaled)
__global__ __launch_bounds__(256)
void wconv_kernel(const float* __restrict__ Wq, const float* __restrict__ Wk,
                  const float* __restrict__ Wv, unsigned short* __restrict__ Wt)
{
    const int t  = blockIdx.x * 256 + threadIdx.x;
    const int n  = t & 127;
    const int kc = (t >> 7) & 127;
    const int p  = t >> 14;
    const float* __restrict__ W = (p == 0) ? Wq : (p == 1) ? Wk : Wv;
    const float sc = (p == 0) ? (1.44269504088896f * 0.0883883476483184f) : 1.0f;
    const float4* src = reinterpret_cast<const float4*>(W + (size_t)n * D_IN + kc * 8);
    float4 a = src[0], b = src[1];
    uint4 o;
    o.x = (uint32_t)f32_to_bf16(a.x * sc) | ((uint32_t)f32_to_bf16(a.y * sc) << 16);
    o.y = (uint32_t)f32_to_bf16(a.z * sc) | ((uint32_t)f32_to_bf16(a.w * sc) << 16);
    o.z = (uint32_t)f32_to_bf16(b.x * sc) | ((uint32_t)f32_to_bf16(b.y * sc) << 16);
    o.w = (uint32_t)f32_to_bf16(b.z * sc) | ((uint32_t)f32_to_bf16(b.w * sc) << 16);
    *reinterpret_cast<uint4*>(Wt + (size_t)t * 8) = o;
}

// ---------------- projection GEMM (R8, passing, ~100us — FROZEN) ----------
#define RBM 32

__global__ __launch_bounds__(256, 2)
void proj_kernel(const float* __restrict__ Xq, const float* __restrict__ Xk,
                 const float* __restrict__ Xv,
                 const unsigned short* __restrict__ Wt,
                 unsigned short* __restrict__ qh, unsigned short* __restrict__ kh,
                 unsigned short* __restrict__ vhT)
{
    const int p = blockIdx.y;
    const float* __restrict__ X = (p == 0) ? Xq : (p == 1) ? Xk : Xv;
    const unsigned short* __restrict__ Wtp = Wt + (size_t)p * 128 * 128 * 8;

    __shared__ unsigned short As[RBM * 1024];   // 64KB  [row][k] bf16, XOR-swizzled
    __shared__ unsigned short Bs[8 * 128 * 8];  // 16KB  [kc_local][n][8], n^kc swizzle

    const int tid  = threadIdx.x;
    const int lane = tid & 63;
    const int wave = tid >> 6;
    const int lrow = lane & 15;
    const int g    = lane >> 4;
    const int wr   = (wave >> 1) * 16;
    const int wc   = (wave & 1) * 64;
    const int wbase = blockIdx.x * RBM;

    // ---- Phase 1: stage 8 full rows per wave (row-linear DRAM reads) ----
    {
        const int r0 = wave * 8;
        const char* rowp = reinterpret_cast<const char*>(
            X + (size_t)(wbase + r0) * D_IN) + lane * 32;
        float4 a0 = *reinterpret_cast<const float4*>(rowp);
        float4 a1 = *reinterpret_cast<const float4*>(rowp + 16);
        float4 a2 = *reinterpret_cast<const float4*>(rowp + 2048);
        float4 a3 = *reinterpret_cast<const float4*>(rowp + 2048 + 16);
        #pragma unroll
        for (int i = 0; i < 8; ++i) {
            float4 c0 = a0, c1 = a1, c2 = a2, c3 = a3;
            if (i < 7) {
                const char* np = rowp + (size_t)(i + 1) * 4096;
                a0 = *reinterpret_cast<const float4*>(np);
                a1 = *reinterpret_cast<const float4*>(np + 16);
                a2 = *reinterpret_cast<const float4*>(np + 2048);
                a3 = *reinterpret_cast<const float4*>(np + 2048 + 16);
            }
            const int r = r0 + i;
            char* base = reinterpret_cast<char*>(As) + r * 2048;
            const int swz = (r & 7) << 4;
            *reinterpret_cast<bf16x8*>(base + ((lane * 16) ^ swz)) = cvt8(c0, c1);
            *reinterpret_cast<bf16x8*>(base + ((1024 + lane * 16) ^ swz)) = cvt8(c2, c3);
        }
    }

    // ---- stage B pass 0 (16KB linear from Wt slice) ----
    {
        const uint4* src = reinterpret_cast<const uint4*>(Wtp) + tid * 4;
        #pragma unroll
        for (int j = 0; j < 4; ++j) {
            uint4 v = src[j];
            const int i  = tid * 4 + j;           // entry index (16B each)
            const int kc = i >> 7, n = i & 127;
            *reinterpret_cast<uint4*>(reinterpret_cast<char*>(Bs) +
                kc * 2048 + ((n ^ kc) * 16)) = v;
        }
    }
    __syncthreads();

    // ---- Phase 2: 16 passes x 2 k-steps, all operands from LDS ----
    f32x4 acc[4];
    #pragma unroll
    for (int ni = 0; ni < 4; ++ni) acc[ni] = (f32x4){0.f, 0.f, 0.f, 0.f};

    const int arow = wr + lrow;
    const char* abase = reinterpret_cast<const char*>(As) + arow * 2048;
    const int aswz = (arow & 7) << 4;

    for (int q = 0; q < 16; ++q) {
        // issue next B slice loads early (async split)
        uint4 nb0, nb1, nb2, nb3;
        if (q < 15) {
            const uint4* src = reinterpret_cast<const uint4*>(
                Wtp + (size_t)(q + 1) * 8192) + tid * 4;
            nb0 = src[0]; nb1 = src[1]; nb2 = src[2]; nb3 = src[3];
        }

        // 2 k-steps from LDS
        #pragma unroll
        for (int s = 0; s < 2; ++s) {
            const int t = 2 * q + s;              // global k-step
            const int kcl = s * 4 + g;            // local kc in Bs
            bf16x8 af = *reinterpret_cast<const bf16x8*>(
                abase + ((t * 64 + g * 16) ^ aswz));
            #pragma unroll
            for (int ni = 0; ni < 4; ++ni) {
                const int n = wc + ni * 16 + lrow;
                bf16x8 bf = *reinterpret_cast<const bf16x8*>(
                    reinterpret_cast<const char*>(Bs) + kcl * 2048 + ((n ^ kcl) * 16));
                acc[ni] = __builtin_amdgcn_mfma_f32_16x16x32_bf16(af, bf, acc[ni], 0, 0, 0);
            }
        }

        __syncthreads();   // all waves done reading Bs(q)
        if (q < 15) {
            #pragma unroll
            for (int j = 0; j < 4; ++j) {
                uint4 v = (j == 0) ? nb0 : (j == 1) ? nb1 : (j == 2) ? nb2 : nb3;
                const int i  = tid * 4 + j;
                const int kc = i >> 7, n = i & 127;
                *reinterpret_cast<uint4*>(reinterpret_cast<char*>(Bs) +
                    kc * 2048 + ((n ^ kc) * 16)) = v;
            }
            __syncthreads();
        }
    }

    // ---- epilogue: col = wc+ni*16+lrow, row = wbase+wr+g*4+r ----
    if (p < 2) {
        unsigned short* __restrict__ Y = (p == 0) ? qh : kh;
        const int rbase = wbase + wr + g * 4;
        #pragma unroll
        for (int ni = 0; ni < 4; ++ni) {
            const int n = wc + ni * 16 + lrow;
            #pragma unroll
            for (int r = 0; r < 4; ++r)
                Y[(size_t)(rbase + r) * D_K + n] = f32_to_bf16(acc[ni][r]);
        }
    } else {
        const int b  = wbase >> 12;
        const int s  = (wbase & 4095) + wr + g * 4;
        #pragma unroll
        for (int ni = 0; ni < 4; ++ni) {
            const int d = wc + ni * 16 + lrow;
            uint2 t;
            t.x = (uint32_t)f32_to_bf16(acc[ni][0]) |
                  ((uint32_t)f32_to_bf16(acc[ni][1]) << 16);
            t.y = (uint32_t)f32_to_bf16(acc[ni][2]) |
                  ((uint32_t)f32_to_bf16(acc[ni][3]) << 16);
            *reinterpret_cast<uint2*>(vhT + ((size_t)(b * D_K + d) << 12) + s) = t;
        }
    }
}

// ---------------- flash attention v10: dbuf K/V via global_load_lds --------
// Staging: gload_lds (fire-and-forget, no VGPR round-trip) into buf^1 issued
// BEFORE computing buf; LDS dest linear, global source pre-swizzled (rule #21)
// so the read side is byte-identical to the R9-proven code. One barrier/tile.
#define KVB 64

__global__ __launch_bounds__(256, 2)
void attn_kernel(const unsigned short* __restrict__ qh,
                 const unsigned short* __restrict__ kh,
                 const unsigned short* __restrict__ vhT,
                 float* __restrict__ out)
{
    __shared__ unsigned short Ks[2][KVB * D_K];   // 2 x 16KB
    __shared__ unsigned short Vs[2][D_K * KVB];   // 2 x 16KB (V^T)
    __shared__ unsigned short Ps[4][16 * KVB];    // per-wave [16][64]

    const int tid  = threadIdx.x;
    const int lane = tid & 63;
    const int wave = tid >> 6;
    const int b    = blockIdx.x & 7;     // batch -> XCD L2 locality
    const int qt   = blockIdx.x >> 3;
    const int q0   = qt * 64 + wave * 16;
    const int lrow = lane & 15;
    const int g4   = (lane >> 4) << 2;
    const int lk16 = (lane >> 4) * 16;

    const unsigned short* __restrict__ Kb = kh + (size_t)b * SEQ * D_K;
    const unsigned short* __restrict__ Vb = vhT + (size_t)b * D_K * SEQ;
    unsigned short* const Pw = Ps[wave];

    // per-lane staging geometry (pre-swizzled global source, linear LDS dest)
    const int kr0  = lane >> 4;                 // K: row-within-4 per instr
    const int kcbp = (lane & 15) * 16;          // K: LDS col byte (linear)
    const int vr0  = lane >> 3;                 // V: row-within-8 per instr
    const int vcbp = (lane & 7) * 16;           // V: LDS col byte (linear)

    // STAGE(buf, tile): 4 K-gloads + 4 V-gloads per wave (wave covers its
    // quarter of each 16KB tile: instr j handles K rows [w*16+j*4 .. +4),
    // V rows [w*32+j*8 .. +8))
    #define STAGE(buf, it_)                                                   \
    do {                                                                      \
        const int s0_ = (it_) * KVB;                                          \
        _Pragma("unroll")                                                     \
        for (int j = 0; j < 4; ++j) {                                         \
            const int blk  = wave * 4 + j;                                    \
            const int krow = blk * 4 + kr0;                                   \
            gload16(reinterpret_cast<const char*>(Kb) +                       \
                        (size_t)(s0_ + krow) * 256 +                          \
                        (kcbp ^ ((krow & 7) << 4)),                           \
                    reinterpret_cast<char*>(Ks[buf]) + blk * 1024);           \
            const int vrow = blk * 8 + vr0;                                   \
            gload16(reinterpret_cast<const char*>(Vb) +                       \
                        (size_t)vrow * (SEQ * 2) + (size_t)s0_ * 2 +          \
                        (vcbp ^ ((vrow & 7) << 4)),                           \
                    reinterpret_cast<char*>(Vs[buf]) + blk * 1024);           \
        }                                                                     \
    } while (0)

    // hoisted Q fragments (16 rows per wave)
    bf16x8 qf[4];
    {
        const char* base = reinterpret_cast<const char*>(
            qh + (size_t)(b * SEQ + q0 + lrow) * D_K);
        #pragma unroll
        for (int ks = 0; ks < 4; ++ks)
            qf[ks] = *reinterpret_cast<const bf16x8*>(base + ks * 64 + lk16);
    }

    f32x4 o[8];
    #pragma unroll
    for (int df = 0; df < 8; ++df) o[df] = (f32x4){0.f, 0.f, 0.f, 0.f};
    float lsum[4] = {0.f, 0.f, 0.f, 0.f};

    // prologue: stage tile 0 into buffer 0
    STAGE(0, 0);
    asm volatile("s_waitcnt vmcnt(0)" ::: "memory");
    __syncthreads();

    int cur = 0;
    for (int it = 0; it < SEQ / KVB; ++it) {
        // issue next-tile staging (fire-and-forget) before compute
        if (it + 1 < SEQ / KVB) STAGE(cur ^ 1, it + 1);

        // QK^T: sc[sf] = Q(16x128) . K(64x128)^T
        f32x4 sc[4];
        #pragma unroll
        for (int sf = 0; sf < 4; ++sf) sc[sf] = (f32x4){0.f, 0.f, 0.f, 0.f};
        #pragma unroll
        for (int ks = 0; ks < 4; ++ks) {
            #pragma unroll
            for (int sf = 0; sf < 4; ++sf) {
                const int row = sf * 16 + lrow;
                bf16x8 kf = *reinterpret_cast<const bf16x8*>(
                    reinterpret_cast<const char*>(Ks[cur]) + row * 256 +
                    ((ks * 64 + lk16) ^ ((row & 7) << 4)));
                sc[sf] = __builtin_amdgcn_mfma_f32_16x16x32_bf16(qf[ks], kf, sc[sf], 0, 0, 0);
            }
        }

        // softmax numerators; spill P to per-wave LDS (same-wave, no barrier)
        #pragma unroll
        for (int sf = 0; sf < 4; ++sf) {
            #pragma unroll
            for (int r = 0; r < 4; ++r) {
                float pv = exp2f(sc[sf][r]);
                lsum[r] += pv;
                const int prow = g4 + r;
                const int pcol = (sf * 16 + lrow) * 2;
                *reinterpret_cast<unsigned short*>(
                    reinterpret_cast<char*>(Pw) + prow * 128 +
                    (pcol ^ ((prow & 7) << 4))) = f32_to_bf16(pv);
            }
        }

        // PV: o[df] += P(16x64) . V(64x128)
        #pragma unroll
        for (int ks = 0; ks < 2; ++ks) {
            bf16x8 pf = *reinterpret_cast<const bf16x8*>(
                reinterpret_cast<const char*>(Pw) + lrow * 128 +
                ((ks * 64 + lk16) ^ ((lrow & 7) << 4)));
            #pragma unroll
            for (int df = 0; df < 8; ++df) {
                const int vr = df * 16 + lrow;
                bf16x8 vf = *reinterpret_cast<const bf16x8*>(
                    reinterpret_cast<const char*>(Vs[cur]) + vr * 128 +
                    ((ks * 64 + lk16) ^ ((vr & 7) << 4)));
                o[df] = __builtin_amdgcn_mfma_f32_16x16x32_bf16(pf, vf, o[df], 0, 0, 0);
            }
        }

        // next tile staged + everyone done reading cur
        asm volatile("s_waitcnt vmcnt(0)" ::: "memory");
        __syncthreads();
        cur ^= 1;
    }
    #undef STAGE

    // finalize: reduce row-sums across the 16-lane group, divide, store fp32
    #pragma unroll
    for (int r = 0; r < 4; ++r) {
        float s = lsum[r];
        s += __shfl_xor(s, 1);
        s += __shfl_xor(s, 2);
        s += __shfl_xor(s, 4);
        s += __shfl_xor(s, 8);
        float inv = 1.0f / s;
        const int row = q0 + g4 + r;
        float* ob = out + (size_t)(b * SEQ + row) * D_K + lrow;
        #pragma unroll
        for (int df = 0; df < 8; ++df)
            ob[df * 16] = o[df][r] * inv;
    }
}

extern "C" void kernel_launch(void* const* d_in, const int* in_sizes, int n_in,
                              void* d_out, int out_size, void* d_ws, size_t ws_size,
                              hipStream_t stream)
{
    (void)in_sizes; (void)n_in; (void)out_size; (void)ws_size;
    const float* q  = (const float*)d_in[0];
    const float* k  = (const float*)d_in[1];
    const float* v  = (const float*)d_in[2];
    const float* Wq = (const float*)d_in[3];
    const float* Wk = (const float*)d_in[4];
    const float* Wv = (const float*)d_in[5];

    unsigned short* qh  = (unsigned short*)d_ws;                 // [32768][128] bf16
    unsigned short* kh  = qh + (size_t)MROWS * D_K;              // [32768][128] bf16
    unsigned short* vhT = kh + (size_t)MROWS * D_K;              // [8][128][4096] bf16
    unsigned short* Wt  = vhT + (size_t)MROWS * D_K;             // [3][128][128][8] bf16

    wconv_kernel<<<dim3(192), 256, 0, stream>>>(Wq, Wk, Wv, Wt);
    proj_kernel<<<dim3(MROWS / RBM, 3), 256, 0, stream>>>(q, k, v, Wt, qh, kh, vhT);
    attn_kernel<<<dim3(NBATCH * (SEQ / 64)), 256, 0, stream>>>(qh, kh, vhT, (float*)d_out);
}

// Round 11
// 226.501 us; speedup vs baseline: 1.9092x; 1.0627x over previous
//
#include <hip/hip_runtime.h>
#include <hip/hip_bf16.h>
#include <stdint.h>

#define D_IN 1024
#define D_K  128
#define NBATCH 8
#define SEQ  4096
#define MROWS (NBATCH * SEQ)

typedef __attribute__((ext_vector_type(8))) short bf16x8;
typedef __attribute__((ext_vector_type(4))) float f32x4;

__device__ __forceinline__ unsigned short f32_to_bf16(float x) {
    union { float f; uint32_t u; } v; v.f = x;
    uint32_t r = 0x7FFFu + ((v.u >> 16) & 1u);
    return (unsigned short)((v.u + r) >> 16);
}

__device__ __forceinline__ bf16x8 cvt8(float4 lo, float4 hi) {
    bf16x8 r;
    r[0] = (short)f32_to_bf16(lo.x); r[1] = (short)f32_to_bf16(lo.y);
    r[2] = (short)f32_to_bf16(lo.z); r[3] = (short)f32_to_bf16(lo.w);
    r[4] = (short)f32_to_bf16(hi.x); r[5] = (short)f32_to_bf16(hi.y);
    r[6] = (short)f32_to_bf16(hi.z); r[7] = (short)f32_to_bf16(hi.w);
    return r;
}

__device__ __forceinline__ void gload16(const void* src, void* lds) {
    __builtin_amdgcn_global_load_lds(
        (const __attribute__((address_space(1))) void*)src,
        (__attribute__((address_space(3))) void*)lds, 16, 0, 0);
}

// ---------------- W pre-convert (unchanged, passing) ----------------
// Wt[p][kc=0..127][n=0..127] = 8 bf16 of W_p[n][kc*8 .. kc*8+8)  (Wq scaled)
__global__ __launch_bounds__(256)
void wconv_kernel(const float* __restrict__ Wq, const float* __restrict__ Wk,
                  const float* __restrict__ Wv, unsigned short* __restrict__ Wt)
{
    const int t  = blockIdx.x * 256 + threadIdx.x;
    const int n  = t & 127;
    const int kc = (t >> 7) & 127;
    const int p  = t >> 14;
    const float* __restrict__ W = (p == 0) ? Wq : (p == 1) ? Wk : Wv;
    const float sc = (p == 0) ? (1.44269504088896f * 0.0883883476483184f) : 1.0f;
    const float4* src = reinterpret_cast<const float4*>(W + (size_t)n * D_IN + kc * 8);
    float4 a = src[0], b = src[1];
    uint4 o;
    o.x = (uint32_t)f32_to_bf16(a.x * sc) | ((uint32_t)f32_to_bf16(a.y * sc) << 16);
    o.y = (uint32_t)f32_to_bf16(a.z * sc) | ((uint32_t)f32_to_bf16(a.w * sc) << 16);
    o.z = (uint32_t)f32_to_bf16(b.x * sc) | ((uint32_t)f32_to_bf16(b.y * sc) << 16);
    o.w = (uint32_t)f32_to_bf16(b.z * sc) | ((uint32_t)f32_to_bf16(b.w * sc) << 16);
    *reinterpret_cast<uint4*>(Wt + (size_t)t * 8) = o;
}

// ---------------- projection GEMM v11: barrier-free k-loop ----------------
// Phase 1 (R5-proven): stage 32 full 4KB rows -> bf16 swizzled LDS [32][1024].
// K-loop (NEW): B read DIRECTLY from Wt in register batches of 16 (4 k-steps
// x 4 ni), statically unrolled (rule #20); each batch's loads are issued as
// its predecessors are consumed -> ~16 loads/wave continuously in flight,
// no barriers, no Bs LDS, no Bs bank conflicts. Waves self-stagger.
#define RBM 32

__global__ __launch_bounds__(256, 2)
void proj_kernel(const float* __restrict__ Xq, const float* __restrict__ Xk,
                 const float* __restrict__ Xv,
                 const unsigned short* __restrict__ Wt,
                 unsigned short* __restrict__ qh, unsigned short* __restrict__ kh,
                 unsigned short* __restrict__ vhT)
{
    const int p = blockIdx.y;
    const float* __restrict__ X = (p == 0) ? Xq : (p == 1) ? Xk : Xv;
    const unsigned short* __restrict__ Wtp = Wt + (size_t)p * 128 * 128 * 8;

    __shared__ unsigned short As[RBM * 1024];   // 64KB [row][k] bf16, XOR-swizzled

    const int tid  = threadIdx.x;
    const int lane = tid & 63;
    const int wave = tid >> 6;
    const int lrow = lane & 15;
    const int g    = lane >> 4;
    const int wr   = (wave >> 1) * 16;
    const int wc   = (wave & 1) * 64;
    const int wbase = blockIdx.x * RBM;

    // ---- Phase 1: stage 8 full rows per wave (row-linear DRAM reads) ----
    {
        const int r0 = wave * 8;
        const char* rowp = reinterpret_cast<const char*>(
            X + (size_t)(wbase + r0) * D_IN) + lane * 32;
        float4 a0 = *reinterpret_cast<const float4*>(rowp);
        float4 a1 = *reinterpret_cast<const float4*>(rowp + 16);
        float4 a2 = *reinterpret_cast<const float4*>(rowp + 2048);
        float4 a3 = *reinterpret_cast<const float4*>(rowp + 2048 + 16);
        #pragma unroll
        for (int i = 0; i < 8; ++i) {
            float4 c0 = a0, c1 = a1, c2 = a2, c3 = a3;
            if (i < 7) {
                const char* np = rowp + (size_t)(i + 1) * 4096;
                a0 = *reinterpret_cast<const float4*>(np);
                a1 = *reinterpret_cast<const float4*>(np + 16);
                a2 = *reinterpret_cast<const float4*>(np + 2048);
                a3 = *reinterpret_cast<const float4*>(np + 2048 + 16);
            }
            const int r = r0 + i;
            char* base = reinterpret_cast<char*>(As) + r * 2048;
            const int swz = (r & 7) << 4;
            *reinterpret_cast<bf16x8*>(base + ((lane * 16) ^ swz)) = cvt8(c0, c1);
            *reinterpret_cast<bf16x8*>(base + ((1024 + lane * 16) ^ swz)) = cvt8(c2, c3);
        }
    }
    __syncthreads();   // the ONLY barrier

    // ---- K-loop: 8 batches x 4 k-steps; B in registers, A from LDS ----
    f32x4 acc[4];
    #pragma unroll
    for (int ni = 0; ni < 4; ++ni) acc[ni] = (f32x4){0.f, 0.f, 0.f, 0.f};

    const int arow = wr + lrow;
    const char* abase = reinterpret_cast<const char*>(As) + arow * 2048;
    const int aswz = (arow & 7) << 4;
    // B entry (kc, n): 16B at Wtp + (kc*128 + n)*8 shorts; kc = 4t + g,
    // n = wc + ni*16 + lrow  (R5/R10-proven layout)
    const unsigned short* __restrict__ wb0 = Wtp + ((size_t)g * 128 + wc + lrow) * 8;

    bf16x8 bb[16];   // batch: bb[s*4+ni] for k-steps bt*4+s — ALL indices static

    // prologue: batch 0 (k-steps 0..3)
    #pragma unroll
    for (int s = 0; s < 4; ++s)
        #pragma unroll
        for (int ni = 0; ni < 4; ++ni)
            bb[s * 4 + ni] = *reinterpret_cast<const bf16x8*>(
                wb0 + ((size_t)s * 4 * 128 + ni * 16) * 8);

    #pragma unroll
    for (int bt = 0; bt < 8; ++bt) {
        #pragma unroll
        for (int s = 0; s < 4; ++s) {
            const int t = bt * 4 + s;
            bf16x8 af = *reinterpret_cast<const bf16x8*>(
                abase + ((t * 64 + g * 16) ^ aswz));
            acc[0] = __builtin_amdgcn_mfma_f32_16x16x32_bf16(af, bb[s * 4 + 0], acc[0], 0, 0, 0);
            acc[1] = __builtin_amdgcn_mfma_f32_16x16x32_bf16(af, bb[s * 4 + 1], acc[1], 0, 0, 0);
            acc[2] = __builtin_amdgcn_mfma_f32_16x16x32_bf16(af, bb[s * 4 + 2], acc[2], 0, 0, 0);
            acc[3] = __builtin_amdgcn_mfma_f32_16x16x32_bf16(af, bb[s * 4 + 3], acc[3], 0, 0, 0);
            // refill this batch slot for batch bt+1 (WAR released by the MFMAs)
            if (bt < 7) {
                const size_t kcb = ((size_t)(bt + 1) * 16 + s * 4) * 128 * 8;
                #pragma unroll
                for (int ni = 0; ni < 4; ++ni)
                    bb[s * 4 + ni] = *reinterpret_cast<const bf16x8*>(
                        wb0 + kcb + (size_t)ni * 16 * 8);
            }
        }
    }

    // ---- epilogue: col = wc+ni*16+lrow, row = wbase+wr+g*4+r ----
    if (p < 2) {
        unsigned short* __restrict__ Y = (p == 0) ? qh : kh;
        const int rbase = wbase + wr + g * 4;
        #pragma unroll
        for (int ni = 0; ni < 4; ++ni) {
            const int n = wc + ni * 16 + lrow;
            #pragma unroll
            for (int r = 0; r < 4; ++r)
                Y[(size_t)(rbase + r) * D_K + n] = f32_to_bf16(acc[ni][r]);
        }
    } else {
        const int b  = wbase >> 12;
        const int s  = (wbase & 4095) + wr + g * 4;
        #pragma unroll
        for (int ni = 0; ni < 4; ++ni) {
            const int d = wc + ni * 16 + lrow;
            uint2 t;
            t.x = (uint32_t)f32_to_bf16(acc[ni][0]) |
                  ((uint32_t)f32_to_bf16(acc[ni][1]) << 16);
            t.y = (uint32_t)f32_to_bf16(acc[ni][2]) |
                  ((uint32_t)f32_to_bf16(acc[ni][3]) << 16);
            *reinterpret_cast<uint2*>(vhT + ((size_t)(b * D_K + d) << 12) + s) = t;
        }
    }
}

// ---------------- flash attention v10 (R10, passing, ~75us — FROZEN) -------
#define KVB 64

__global__ __launch_bounds__(256, 2)
void attn_kernel(const unsigned short* __restrict__ qh,
                 const unsigned short* __restrict__ kh,
                 const unsigned short* __restrict__ vhT,
                 float* __restrict__ out)
{
    __shared__ unsigned short Ks[2][KVB * D_K];   // 2 x 16KB
    __shared__ unsigned short Vs[2][D_K * KVB];   // 2 x 16KB (V^T)
    __shared__ unsigned short Ps[4][16 * KVB];    // per-wave [16][64]

    const int tid  = threadIdx.x;
    const int lane = tid & 63;
    const int wave = tid >> 6;
    const int b    = blockIdx.x & 7;     // batch -> XCD L2 locality
    const int qt   = blockIdx.x >> 3;
    const int q0   = qt * 64 + wave * 16;
    const int lrow = lane & 15;
    const int g4   = (lane >> 4) << 2;
    const int lk16 = (lane >> 4) * 16;

    const unsigned short* __restrict__ Kb = kh + (size_t)b * SEQ * D_K;
    const unsigned short* __restrict__ Vb = vhT + (size_t)b * D_K * SEQ;
    unsigned short* const Pw = Ps[wave];

    const int kr0  = lane >> 4;
    const int kcbp = (lane & 15) * 16;
    const int vr0  = lane >> 3;
    const int vcbp = (lane & 7) * 16;

    #define STAGE(buf, it_)                                                   \
    do {                                                                      \
        const int s0_ = (it_) * KVB;                                          \
        _Pragma("unroll")                                                     \
        for (int j = 0; j < 4; ++j) {                                         \
            const int blk  = wave * 4 + j;                                    \
            const int krow = blk * 4 + kr0;                                   \
            gload16(reinterpret_cast<const char*>(Kb) +                       \
                        (size_t)(s0_ + krow) * 256 +                          \
                        (kcbp ^ ((krow & 7) << 4)),                           \
                    reinterpret_cast<char*>(Ks[buf]) + blk * 1024);           \
            const int vrow = blk * 8 + vr0;                                   \
            gload16(reinterpret_cast<const char*>(Vb) +                       \
                        (size_t)vrow * (SEQ * 2) + (size_t)s0_ * 2 +          \
                        (vcbp ^ ((vrow & 7) << 4)),                           \
                    reinterpret_cast<char*>(Vs[buf]) + blk * 1024);           \
        }                                                                     \
    } while (0)

    bf16x8 qf[4];
    {
        const char* base = reinterpret_cast<const char*>(
            qh + (size_t)(b * SEQ + q0 + lrow) * D_K);
        #pragma unroll
        for (int ks = 0; ks < 4; ++ks)
            qf[ks] = *reinterpret_cast<const bf16x8*>(base + ks * 64 + lk16);
    }

    f32x4 o[8];
    #pragma unroll
    for (int df = 0; df < 8; ++df) o[df] = (f32x4){0.f, 0.f, 0.f, 0.f};
    float lsum[4] = {0.f, 0.f, 0.f, 0.f};

    STAGE(0, 0);
    asm volatile("s_waitcnt vmcnt(0)" ::: "memory");
    __syncthreads();

    int cur = 0;
    for (int it = 0; it < SEQ / KVB; ++it) {
        if (it + 1 < SEQ / KVB) STAGE(cur ^ 1, it + 1);

        f32x4 sc[4];
        #pragma unroll
        for (int sf = 0; sf < 4; ++sf) sc[sf] = (f32x4){0.f, 0.f, 0.f, 0.f};
        #pragma unroll
        for (int ks = 0; ks < 4; ++ks) {
            #pragma unroll
            for (int sf = 0; sf < 4; ++sf) {
                const int row = sf * 16 + lrow;
                bf16x8 kf = *reinterpret_cast<const bf16x8*>(
                    reinterpret_cast<const char*>(Ks[cur]) + row * 256 +
                    ((ks * 64 + lk16) ^ ((row & 7) << 4)));
                sc[sf] = __builtin_amdgcn_mfma_f32_16x16x32_bf16(qf[ks], kf, sc[sf], 0, 0, 0);
            }
        }

        #pragma unroll
        for (int sf = 0; sf < 4; ++sf) {
            #pragma unroll
            for (int r = 0; r < 4; ++r) {
                float pv = exp2f(sc[sf][r]);
                lsum[r] += pv;
                const int prow = g4 + r;
                const int pcol = (sf * 16 + lrow) * 2;
                *reinterpret_cast<unsigned short*>(
                    reinterpret_cast<char*>(Pw) + prow * 128 +
                    (pcol ^ ((prow & 7) << 4))) = f32_to_bf16(pv);
            }
        }

        #pragma unroll
        for (int ks = 0; ks < 2; ++ks) {
            bf16x8 pf = *reinterpret_cast<const bf16x8*>(
                reinterpret_cast<const char*>(Pw) + lrow * 128 +
                ((ks * 64 + lk16) ^ ((lrow & 7) << 4)));
            #pragma unroll
            for (int df = 0; df < 8; ++df) {
                const int vr = df * 16 + lrow;
                bf16x8 vf = *reinterpret_cast<const bf16x8*>(
                    reinterpret_cast<const char*>(Vs[cur]) + vr * 128 +
                    ((ks * 64 + lk16) ^ ((vr & 7) << 4)));
                o[df] = __builtin_amdgcn_mfma_f32_16x16x32_bf16(pf, vf, o[df], 0, 0, 0);
            }
        }

        asm volatile("s_waitcnt vmcnt(0)" ::: "memory");
        __syncthreads();
        cur ^= 1;
    }
    #undef STAGE

    #pragma unroll
    for (int r = 0; r < 4; ++r) {
        float s = lsum[r];
        s += __shfl_xor(s, 1);
        s += __shfl_xor(s, 2);
        s += __shfl_xor(s, 4);
        s += __shfl_xor(s, 8);
        float inv = 1.0f / s;
        const int row = q0 + g4 + r;
        float* ob = out + (size_t)(b * SEQ + row) * D_K + lrow;
        #pragma unroll
        for (int df = 0; df < 8; ++df)
            ob[df * 16] = o[df][r] * inv;
    }
}

extern "C" void kernel_launch(void* const* d_in, const int* in_sizes, int n_in,
                              void* d_out, int out_size, void* d_ws, size_t ws_size,
                              hipStream_t stream)
{
    (void)in_sizes; (void)n_in; (void)out_size; (void)ws_size;
    const float* q  = (const float*)d_in[0];
    const float* k  = (const float*)d_in[1];
    const float* v  = (const float*)d_in[2];
    const float* Wq = (const float*)d_in[3];
    const float* Wk = (const float*)d_in[4];
    const float* Wv = (const float*)d_in[5];

    unsigned short* qh  = (unsigned short*)d_ws;                 // [32768][128] bf16
    unsigned short* kh  = qh + (size_t)MROWS * D_K;              // [32768][128] bf16
    unsigned short* vhT = kh + (size_t)MROWS * D_K;              // [8][128][4096] bf16
    unsigned short* Wt  = vhT + (size_t)MROWS * D_K;             // [3][128][128][8] bf16

    wconv_kernel<<<dim3(192), 256, 0, stream>>>(Wq, Wk, Wv, Wt);
    proj_kernel<<<dim3(MROWS / RBM, 3), 256, 0, stream>>>(q, k, v, Wt, qh, kh, vhT);
    attn_kernel<<<dim3(NBATCH * (SEQ / 64)), 256, 0, stream>>>(qh, kh, vhT, (float*)d_out);
}